// Round 11
// baseline (204.597 us; speedup 1.0000x reference)
//
#include <hip/hip_runtime.h>

#define Bn 8
#define Nn 4096
#define Pn 4096
#define Kn 32
#define Cn 128

using float4v = __attribute__((ext_vector_type(4))) float;
using short8  = __attribute__((ext_vector_type(8))) short;

__device__ __forceinline__ unsigned short bf16b(float f) {
  union { float f; unsigned u; } v; v.f = f;
  unsigned r = v.u + 0x7FFFu + ((v.u >> 16) & 1u);   // round-nearest-even
  return (unsigned short)(r >> 16);
}

// (hi16(x)) | (hi16(y)<<16) — truncating f32->bf16 pair pack, one v_perm_b32
__device__ __forceinline__ unsigned pkhi(float x, float y) {
  return __builtin_amdgcn_perm(__float_as_uint(y), __float_as_uint(x), 0x07060302u);
}

// ---------------------------------------------------------------------------
// prep: blocks 0-63: WlT[n][k] = bf16(Wl[k][n]); blocks 64-95: xyz copy into
// d_out (+ block 64 zeroes gacc).
// ---------------------------------------------------------------------------
__global__ __launch_bounds__(256) void prep(const float* __restrict__ Wl,
                                            unsigned short* __restrict__ WlT,
                                            const float* __restrict__ xyz,
                                            float* __restrict__ out,
                                            float* __restrict__ gacc) {
  __shared__ unsigned short tile[128 * 33];   // [n][kl], +1 pad
  const int t = threadIdx.x, blk = blockIdx.x;
  if (blk < 64) {
#pragma unroll
    for (int i = 0; i < 16; ++i) {
      int idx = i * 256 + t;                  // 0..4095
      int kl = idx >> 7, n = idx & 127;
      tile[n * 33 + kl] = bf16b(Wl[(size_t)(blk * 32 + kl) * 128 + n]);
    }
    __syncthreads();
#pragma unroll
    for (int i = 0; i < 16; ++i) {
      int idx = i * 256 + t;
      int n = idx >> 5, kl = idx & 31;
      WlT[(size_t)n * 2048 + blk * 32 + kl] = tile[n * 33 + kl];
    }
  } else {
    if (blk == 64) gacc[t] = 0.f;
    const int i0 = (blk - 64) * 3072 + t * 12;   // 32 blocks x 3072 f32
#pragma unroll
    for (int i = 0; i < 3; ++i)
      *(float4v*)(out + i0 + i * 4) = *(const float4v*)(xyz + i0 + i * 4);
  }
}

// ---------------------------------------------------------------------------
// fused v9 (wide DMA + deep lookahead): 1024 blocks x 4 waves x 32 points.
// Gathers as global_load_lds WIDTH 16: 16 rows x 16B/lane per instruction ->
// 2 instr/point-ct (was 8) -> 4x less VMEM queue pressure. nlds stored
// PERMUTED (slot(r) = (r&7)*4 + r>>3) so the lane-linear DMA dest yields a
// slab whose FIN read (f[j] = slab[j*64+lane]) is bit-identical to the
// R8/R10 conflict-free pattern. Ring of 3 point-buffers/wave + cross-barrier
// prefetch of next ct's 3 points -> issue-to-consume distance 2-3 FIN bodies
// (was 1), counted vmcnt(4,4,4,4,4,4,2,0). Phase A/Mlds/epilogue = R7
// verbatim (verified). LDS 45 KB -> 3 blocks/CU.
// ---------------------------------------------------------------------------
__global__ __launch_bounds__(256, 4) void fused(
    const float* __restrict__ points, const float* __restrict__ lc,
    const int* __restrict__ nl, const int* __restrict__ didx,
    const float* __restrict__ Ww, const float* __restrict__ bwv,
    const unsigned short* __restrict__ WlT, const float* __restrict__ blv,
    float* __restrict__ xout, float* __restrict__ gacc) {
  __shared__ float slab[4][3][512];           // 24 KB: per-wave ring of 3
  __shared__ unsigned short Mlds[32 * 256];   // 16 KB, two-sided XOR swizzle
  __shared__ int nldsP[32 * 32];              // 4 KB, PERMUTED + pre-shifted
  __shared__ float red[256];                  // 1 KB

  const int t = threadIdx.x, lane = t & 63, w = t >> 6;
  const int l15 = lane & 15, q = lane >> 4;
  const int b = blockIdx.x & 7;               // XCD-affine batch
  const int pg = blockIdx.x >> 3;             // 0..127
  const int p0 = pg * 32;
  const int db = didx[b];
  const char* __restrict__ pbase = (const char*)(points + (size_t)db * Nn * Cn);

  // stage neighbor ids: PERMUTED (slot = (r&7)*4 | r>>3), pre-shifted <<9
  {
    const int pk0 = (db * Pn + p0) * Kn;
    int4 nv = *(const int4*)(nl + pk0 + t * 4);
    const int pi = t >> 3;            // (t*4)>>5
    const int r0 = (t << 2) & 31;     // aligned 4, same 8-group
    nldsP[pi * 32 + ((((r0 + 0) & 7) << 2) | ((r0 + 0) >> 3))] = nv.x << 9;
    nldsP[pi * 32 + ((((r0 + 1) & 7) << 2) | ((r0 + 1) >> 3))] = nv.y << 9;
    nldsP[pi * 32 + ((((r0 + 2) & 7) << 2) | ((r0 + 2) >> 3))] = nv.z << 9;
    nldsP[pi * 32 + ((((r0 + 3) & 7) << 2) | ((r0 + 3) >> 3))] = nv.w << 9;
  }

  const float Ww0 = Ww[l15], Ww1 = Ww[16 + l15], Ww2 = Ww[32 + l15];
  const float bw0 = bwv[l15];

  // weight A-frags for my 8 points: A[m=w_out=l15][k=q*8+j]
  short8 af[8];
#pragma unroll
  for (int i = 0; i < 8; ++i) {
    const int p = p0 + w * 8 + i;
    const int pk = (db * Pn + p) * Kn;
    const float* __restrict__ lcp = lc + (size_t)(pk + q * 8) * 3;
    float la[24];
#pragma unroll
    for (int v = 0; v < 6; ++v) *(float4v*)&la[v * 4] = *(const float4v*)(lcp + v * 4);
#pragma unroll
    for (int j = 0; j < 8; ++j) {
      float ww = bw0 + la[3 * j] * Ww0 + la[3 * j + 1] * Ww1 + la[3 * j + 2] * Ww2;
      af[i][j] = (short)bf16b(ww);
    }
  }

  float4v acc[2][2];
#pragma unroll
  for (int pt = 0; pt < 2; ++pt)
#pragma unroll
    for (int nt = 0; nt < 2; ++nt) acc[pt][nt] = (float4v){0.f, 0.f, 0.f, 0.f};

  __syncthreads();   // nldsP ready

  // my n-slice: channels w*32 .. w*32+31
  const unsigned short* __restrict__ bpt =
      WlT + (size_t)(w * 32 + l15) * 2048 + q * 8;
  const int idx0 = lane >> 2;                 // physical slot within half
  const unsigned subo = (unsigned)((lane & 3) * 16);

#define WAITV4 asm volatile("s_waitcnt vmcnt(4)" ::: "memory")
#define WAITV2 asm volatile("s_waitcnt vmcnt(2)" ::: "memory")
#define WAITV0 asm volatile("s_waitcnt vmcnt(0)" ::: "memory")
#define LGKM0  asm volatile("s_waitcnt lgkmcnt(0)" ::: "memory")
#define SBAR   __builtin_amdgcn_sched_barrier(0)

// 2 wide LDS-DMA for point (i), chunk (ct) into slab[w][bsel] (2KB)
#define DMA16(i, ct, bsel)                                                 \
  {                                                                        \
    const int pi_ = w * 8 + (i);                                           \
    const int a0_ = nldsP[pi_ * 32 + idx0];                                \
    const int a1_ = nldsP[pi_ * 32 + 16 + idx0];                           \
    __builtin_amdgcn_global_load_lds(                                      \
        (const __attribute__((address_space(1))) unsigned int*)            \
            (pbase + ((unsigned)a0_ + subo + (unsigned)((ct) * 64))),      \
        (__attribute__((address_space(3))) unsigned int*)                  \
            (&slab[w][bsel][0]),                                           \
        16, 0, 0);                                                        \
    __builtin_amdgcn_global_load_lds(                                      \
        (const __attribute__((address_space(1))) unsigned int*)            \
            (pbase + ((unsigned)a1_ + subo + (unsigned)((ct) * 64))),      \
        (__attribute__((address_space(3))) unsigned int*)                  \
            (&slab[w][bsel][256]),                                         \
        16, 0, 0);                                                        \
  }

// read slab ring buffer (buf) then pack + step1 MFMA + swizzled Mlds write
#define FIN(i, buf)                                                       \
  {                                                                        \
    const int pi_ = w * 8 + (i);                                           \
    float f_[8];                                                           \
    const float* ls_ = &slab[w][buf][(unsigned)lane];                      \
    _Pragma("unroll") for (int j = 0; j < 8; ++j) f_[j] = ls_[j * 64];     \
    union { short8 s; unsigned u[4]; } bv_;                                \
    bv_.u[0] = pkhi(f_[0], f_[1]);                                         \
    bv_.u[1] = pkhi(f_[2], f_[3]);                                         \
    bv_.u[2] = pkhi(f_[4], f_[5]);                                         \
    bv_.u[3] = pkhi(f_[6], f_[7]);                                         \
    float4v d_ = {0.f, 0.f, 0.f, 0.f};                                     \
    d_ = __builtin_amdgcn_mfma_f32_16x16x32_bf16(af[i], bv_.s, d_, 0, 0, 0); \
    const unsigned off_ = (unsigned)(pi_ * 512 + ((l15 * 32 + q * 8) ^     \
        ((((pi_ & 7) ^ (l15 & 7)) & 7) << 4)));                            \
    uint2 u_;                                                              \
    u_.x = pkhi(d_[0], d_[1]);                                             \
    u_.y = pkhi(d_[2], d_[3]);                                             \
    *(uint2*)((char*)Mlds + off_) = u_;                                    \
  }

  // prologue: ct=0 points 0-2 in flight (6 instructions)
  SBAR;
  DMA16(0, 0, 0)
  DMA16(1, 0, 1)
  DMA16(2, 0, 2)

  for (int ct = 0; ct < 8; ++ct) {
    // ---- phase B: ring-3, counted waits 4,4,4,4,4,4,2,0
    WAITV4; SBAR; FIN(0, 0) SBAR; DMA16(3, ct, 0)
    WAITV4; SBAR; FIN(1, 1) SBAR; DMA16(4, ct, 1)
    WAITV4; SBAR; FIN(2, 2) SBAR; DMA16(5, ct, 2)
    WAITV4; SBAR; FIN(3, 0) SBAR; DMA16(6, ct, 0)
    WAITV4; SBAR; FIN(4, 1) SBAR; DMA16(7, ct, 1)
    WAITV4; SBAR; FIN(5, 2)
    WAITV2; SBAR; FIN(6, 0)
    WAITV0; SBAR; FIN(7, 1)
    LGKM0; SBAR;
    __builtin_amdgcn_s_barrier();             // barrier 1: Mlds ready
    // ---- phase A: Y += Mchunk @ WlT-chunk for my 32 channels (R7 verbatim)
    const unsigned short* __restrict__ bp = bpt + ct * 256;
    short8 b0A = *(const short8*)(bp);
    short8 b1A = *(const short8*)(bp + 32768);
    __builtin_amdgcn_s_setprio(1);
#pragma unroll
    for (int ks = 0; ks < 8; ++ks) {
      short8 b0B, b1B;
      if (ks < 7) {
        b0B = *(const short8*)(bp + (ks + 1) * 32);
        b1B = *(const short8*)(bp + 32768 + (ks + 1) * 32);
      }
      const unsigned ax = (unsigned)((ks * 64 + q * 16) ^
          ((((l15 & 7) ^ ((ks * 2 + (q >> 1)) & 7)) & 7) << 4));
      short8 a0 = *(const short8*)((const char*)Mlds + l15 * 512 + ax);
      short8 a1 = *(const short8*)((const char*)Mlds + (16 + l15) * 512 + ax);
      acc[0][0] = __builtin_amdgcn_mfma_f32_16x16x32_bf16(a0, b0A, acc[0][0], 0, 0, 0);
      acc[0][1] = __builtin_amdgcn_mfma_f32_16x16x32_bf16(a0, b1A, acc[0][1], 0, 0, 0);
      acc[1][0] = __builtin_amdgcn_mfma_f32_16x16x32_bf16(a1, b0A, acc[1][0], 0, 0, 0);
      acc[1][1] = __builtin_amdgcn_mfma_f32_16x16x32_bf16(a1, b1A, acc[1][1], 0, 0, 0);
      b0A = b0B; b1A = b1B;
    }
    __builtin_amdgcn_s_setprio(0);
    // cross-barrier prefetch: next ct's points 0-2 (bufs 0-2 were last read
    // at FIN(6)/FIN(7)/FIN(5) of THIS ct, all before phase A; all phase-A
    // b-loads already consumed -> in-order vmcnt is clean)
    if (ct < 7) {
      SBAR;
      DMA16(0, ct + 1, 0)
      DMA16(1, ct + 1, 1)
      DMA16(2, ct + 1, 2)
    }
    SBAR;
    __builtin_amdgcn_s_barrier();             // barrier 2: Mlds reusable
  }
#undef DMA16
#undef FIN
#undef WAITV4
#undef WAITV2
#undef WAITV0
#undef LGKM0
#undef SBAR

  // epilogue: bias, transposed store (B,C,P), disjoint per-wave channel stats
#pragma unroll
  for (int nt = 0; nt < 2; ++nt) {
    const int ch = w * 32 + nt * 16 + l15;
    const float bb = blv[ch];
    float s = 0.f, sq = 0.f;
#pragma unroll
    for (int pt = 0; pt < 2; ++pt) {
      float4v o;
#pragma unroll
      for (int r = 0; r < 4; ++r) {
        float v = acc[pt][nt][r] + bb; o[r] = v; s += v; sq += v * v;
      }
      *(float4v*)(xout + ((size_t)(b * Cn + ch)) * Pn + p0 + pt * 16 + q * 4) = o;
    }
    s += __shfl_xor(s, 16); s += __shfl_xor(s, 32);
    sq += __shfl_xor(sq, 16); sq += __shfl_xor(sq, 32);
    if (lane < 16) { red[ch] = s; red[128 + ch] = sq; }
  }
  __syncthreads();
  atomicAdd(&gacc[t], red[t]);
}

// ---------------------------------------------------------------------------
// finalize: layernorm (per-channel over B*P) + relu, in place on x chunk
// ---------------------------------------------------------------------------
__global__ __launch_bounds__(256) void finalize_ln(float* __restrict__ x,
                                                   const float* __restrict__ gacc,
                                                   const float* __restrict__ gamma,
                                                   const float* __restrict__ beta) {
  const int idx = blockIdx.x * 256 + threadIdx.x;
  const int fi = idx * 4;
  const int c = (fi >> 12) & 127;
  const float inv = 1.f / 32768.f;
  const float mean = gacc[c] * inv;
  const float var = gacc[128 + c] * inv - mean * mean;
  const float scale = rsqrtf(var + 1e-5f) * gamma[c];
  const float shift = beta[c] - mean * scale;
  float4v v = *(float4v*)(x + fi);
#pragma unroll
  for (int r = 0; r < 4; ++r) v[r] = fmaxf(v[r] * scale + shift, 0.f);
  *(float4v*)(x + fi) = v;
}

extern "C" void kernel_launch(void* const* d_in, const int* in_sizes, int n_in,
                              void* d_out, int out_size, void* d_ws, size_t ws_size,
                              hipStream_t stream) {
  const float* xyz    = (const float*)d_in[0];
  const float* points = (const float*)d_in[1];
  const float* lc     = (const float*)d_in[2];
  const int*   nl     = (const int*)d_in[3];
  const int*   didx   = (const int*)d_in[4];
  const float* Ww     = (const float*)d_in[5];
  const float* bw     = (const float*)d_in[6];
  const float* Wl     = (const float*)d_in[7];
  const float* bl     = (const float*)d_in[8];
  const float* gamma  = (const float*)d_in[9];
  const float* beta   = (const float*)d_in[10];

  float* out  = (float*)d_out;
  float* xout = out + (size_t)Bn * Pn * 3;                       // x chunk (B,C,P)
  unsigned short* WlT = (unsigned short*)d_ws;                   // 512 KB
  float* gacc = (float*)((char*)d_ws + (size_t)512 * 1024);      // 1 KB

  prep<<<96, 256, 0, stream>>>(Wl, WlT, xyz, out, gacc);
  fused<<<1024, 256, 0, stream>>>(points, lc, nl, didx, Ww, bw, WlT, bl,
                                  xout, gacc);
  finalize_ln<<<4096, 256, 0, stream>>>(xout, gacc, gamma, beta);
}